// Round 1
// baseline (2688.980 us; speedup 1.0000x reference)
//
#include <hip/hip_runtime.h>
#include <math.h>

#define T_STEPS 256
#define BATCH   256
#define DDIM    128
#define NH      10

// ---------- wave-wide helpers (wave64) ----------
__device__ __forceinline__ float wave_sum(float v){
  v += __shfl_xor(v, 1, 64);
  v += __shfl_xor(v, 2, 64);
  v += __shfl_xor(v, 4, 64);
  v += __shfl_xor(v, 8, 64);
  v += __shfl_xor(v, 16, 64);
  v += __shfl_xor(v, 32, 64);
  return v;
}

// RX on a reg-bit wire (bit BIT of the 4 low index bits). Pure VALU.
template<int BIT>
__device__ __forceinline__ void rx_reg(float c, float s, float* re, float* im){
  #pragma unroll
  for (int r = 0; r < 16; ++r){
    if (r & (1 << BIT)) continue;
    const int r1 = r | (1 << BIT);
    float a0 = re[r], b0 = im[r], a1 = re[r1], b1 = im[r1];
    re[r]  = fmaf(c, a0,  s * b1);
    im[r]  = fmaf(c, b0, -s * a1);
    re[r1] = fmaf(c, a1,  s * b0);
    im[r1] = fmaf(c, b1, -s * a0);
  }
}

// RX on a lane-bit wire: partner value via shfl_xor; same update formula on
// both sides of the pair (derived: new_re = c*my_re + s*other_im,
//                                  new_im = c*my_im - s*other_re).
__device__ __forceinline__ void rx_lane(float c, float s, int mask, float* re, float* im){
  #pragma unroll
  for (int r = 0; r < 16; ++r){
    float oa = __shfl_xor(re[r], mask, 64);
    float ob = __shfl_xor(im[r], mask, 64);
    re[r] = fmaf(c, re[r],  s * ob);
    im[r] = fmaf(c, im[r], -s * oa);
  }
}

// One RX layer over all 10 wires. Wire w <-> index bit 9-w.
// Lane bits 5..0 = wires 0..5 (shuffle masks 32..1); reg bits 3..0 = wires 6..9.
__device__ __forceinline__ void rx_layer(const float* c, const float* s, float* re, float* im){
  rx_lane(c[0], s[0], 32, re, im);
  rx_lane(c[1], s[1], 16, re, im);
  rx_lane(c[2], s[2],  8, re, im);
  rx_lane(c[3], s[3],  4, re, im);
  rx_lane(c[4], s[4],  2, re, im);
  rx_lane(c[5], s[5],  1, re, im);
  rx_reg<3>(c[6], s[6], re, im);
  rx_reg<2>(c[7], s[7], re, im);
  rx_reg<1>(c[8], s[8], re, im);
  rx_reg<0>(c[9], s[9], re, im);
}

// Full CNOT ring layer (0,1)(1,2)...(8,9)(9,0), applied sequentially, as the
// composite GF(2)-linear index permutation, factored into 4 cheap moves:
//  (1) 5 lane-lane CNOTs (bits 9..4 prefix-xor chain): gather lane ^ (lane>>1)
//  (2) CNOT(bit4 -> bit3): lanes with bit0 set swap regs r <-> r^8
//  (3) 3 reg-reg CNOTs: static reg permutation new[n] = old[n ^ (n>>1)]
//  (4) CNOT(bit0 -> bit9): odd regs exchange across lane^32
__device__ __forceinline__ void cnot_layer(int lane, float* re, float* im){
  int src = lane ^ (lane >> 1);
  #pragma unroll
  for (int r = 0; r < 16; ++r){
    re[r] = __shfl(re[r], src, 64);
    im[r] = __shfl(im[r], src, 64);
  }
  bool flip = (lane & 1);
  #pragma unroll
  for (int r = 0; r < 8; ++r){
    float ta = re[r],   tb = im[r];
    float ua = re[r+8], ub = im[r+8];
    re[r]   = flip ? ua : ta;  im[r]   = flip ? ub : tb;
    re[r+8] = flip ? ta : ua;  im[r+8] = flip ? tb : ub;
  }
  float tr[16], ti[16];
  #pragma unroll
  for (int n = 0; n < 16; ++n){ tr[n] = re[n ^ (n >> 1)]; ti[n] = im[n ^ (n >> 1)]; }
  #pragma unroll
  for (int n = 0; n < 16; ++n){ re[n] = tr[n]; im[n] = ti[n]; }
  #pragma unroll
  for (int r = 1; r < 16; r += 2){
    re[r] = __shfl_xor(re[r], 32, 64);
    im[r] = __shfl_xor(im[r], 32, 64);
  }
}

// One block per batch element b; 4 waves = 4 LSTM gates (0=f,1=i,2=g,3=o).
// Each wave holds one 10-qubit statevector: 16 complex amps per lane.
__global__ void __launch_bounds__(256, 1)
qlstm_kernel(const float* __restrict__ inp, const float* __restrict__ rxp,
             const float* __restrict__ Wf, const float* __restrict__ bf,
             const float* __restrict__ Wi, const float* __restrict__ bi,
             const float* __restrict__ Wg, const float* __restrict__ bg,
             const float* __restrict__ Wo, const float* __restrict__ bo,
             float* __restrict__ out)
{
  const int b    = blockIdx.x;
  const int tid  = threadIdx.x;
  const int g    = tid >> 6;     // gate index, wave-uniform
  const int lane = tid & 63;

  __shared__ float gateV[4][NH];
  __shared__ float hxS[NH];
  __shared__ float cxS[NH];

  if (tid < NH){ hxS[tid] = 0.f; cxS[tid] = 0.f; }

  const float* Wp = (g == 0) ? Wf : (g == 1) ? Wi : (g == 2) ? Wg : Wo;
  const float* bp = (g == 0) ? bf : (g == 1) ? bi : (g == 2) ? bg : bo;

  // Per-lane slices of W (rows = 10 wires, 138 cols): cols [lane], [64+lane],
  // and for lanes 0..9 the hx columns [128+lane].
  float wA[NH], wB[NH], wC[NH], bs[NH];
  #pragma unroll
  for (int w = 0; w < NH; ++w){
    wA[w] = Wp[w*138 + lane];
    wB[w] = Wp[w*138 + 64 + lane];
    wC[w] = (lane < NH) ? Wp[w*138 + 128 + lane] : 0.f;
    bs[w] = bp[w];
  }

  // Fixed variational RX angles (precise one-time trig).
  float pc[NH], ps[NH];
  #pragma unroll
  for (int w = 0; w < NH; ++w){
    float th = 0.5f * rxp[w];
    pc[w] = cosf(th);
    ps[w] = sinf(th);
  }

  const int kl = __popc(lane) & 3;   // lane contribution to (-i)^popc phase

  __syncthreads();

  #pragma unroll 1
  for (int t = 0; t < T_STEPS; ++t){
    // ---- gate pre-activation angles: theta_w = b[w] + comb . W[w,:] ----
    const float* xrow = inp + ((size_t)t * BATCH + b) * DDIM;
    float xa = xrow[lane];
    float xb = xrow[64 + lane];
    float hv = (lane < NH) ? hxS[lane] : 0.f;

    float dc[NH], dsn[NH];
    #pragma unroll
    for (int w = 0; w < NH; ++w){
      float p  = fmaf(xa, wA[w], fmaf(xb, wB[w], hv * wC[w]));
      float th = 0.5f * (bs[w] + wave_sum(p));
      dc[w]  = __cosf(th);
      dsn[w] = __sinf(th);
    }

    // ---- build product state RX(x)|0..0>: amp(i) = prod * (-i)^popc(i) ----
    float t67[4], t89[4];
    t67[0] = dc[6]*dc[7];  t67[1] = dc[6]*dsn[7];  t67[2] = dsn[6]*dc[7];  t67[3] = dsn[6]*dsn[7];
    t89[0] = dc[8]*dc[9];  t89[1] = dc[8]*dsn[9];  t89[2] = dsn[8]*dc[9];  t89[3] = dsn[8]*dsn[9];

    float lp = ((lane >> 5) & 1 ? dsn[0] : dc[0]);
    lp *= ((lane >> 4) & 1 ? dsn[1] : dc[1]);
    lp *= ((lane >> 3) & 1 ? dsn[2] : dc[2]);
    lp *= ((lane >> 2) & 1 ? dsn[3] : dc[3]);
    lp *= ((lane >> 1) & 1 ? dsn[4] : dc[4]);
    lp *= ((lane >> 0) & 1 ? dsn[5] : dc[5]);

    float lre = (kl == 0) ?  lp : (kl == 2) ? -lp : 0.f;
    float lim = (kl == 1) ? -lp : (kl == 3) ?  lp : 0.f;

    float re[16], im[16];
    #pragma unroll
    for (int r = 0; r < 16; ++r){
      float rp = t67[r >> 2] * t89[r & 3];
      const int kr = __popc(r) & 3;   // compile-time after unroll
      float ar, ai;
      if      (kr == 0){ ar =  lre; ai =  lim; }
      else if (kr == 1){ ar =  lim; ai = -lre; }
      else if (kr == 2){ ar = -lre; ai = -lim; }
      else             { ar = -lim; ai =  lre; }
      re[r] = rp * ar;
      im[r] = rp * ai;
    }

    // ---- 2 variational layers: RX layer + CNOT ring ----
    #pragma unroll
    for (int d = 0; d < 2; ++d){
      rx_layer(pc, ps, re, im);
      cnot_layer(lane, re, im);
    }

    // ---- PauliZ expectations ----
    float tot = 0.f, p6 = 0.f, p7 = 0.f, p8 = 0.f, p9 = 0.f;
    #pragma unroll
    for (int r = 0; r < 16; ++r){
      float p = fmaf(re[r], re[r], im[r]*im[r]);
      tot += p;
      p6 += (r & 8) ? -p : p;
      p7 += (r & 4) ? -p : p;
      p8 += (r & 2) ? -p : p;
      p9 += (r & 1) ? -p : p;
    }
    float e[NH];
    e[0] = wave_sum(((lane >> 5) & 1) ? -tot : tot);
    e[1] = wave_sum(((lane >> 4) & 1) ? -tot : tot);
    e[2] = wave_sum(((lane >> 3) & 1) ? -tot : tot);
    e[3] = wave_sum(((lane >> 2) & 1) ? -tot : tot);
    e[4] = wave_sum(((lane >> 1) & 1) ? -tot : tot);
    e[5] = wave_sum(( lane       & 1) ? -tot : tot);
    e[6] = wave_sum(p6);
    e[7] = wave_sum(p7);
    e[8] = wave_sum(p8);
    e[9] = wave_sum(p9);

    // ---- activation (wave-uniform branch) ----
    float act[NH];
    if (g == 2){
      #pragma unroll
      for (int w = 0; w < NH; ++w){
        float e2 = __expf(2.f * e[w]);
        act[w] = (e2 - 1.f) / (e2 + 1.f);
      }
    } else {
      #pragma unroll
      for (int w = 0; w < NH; ++w){
        act[w] = 1.f / (1.f + __expf(-e[w]));
      }
    }
    if (lane == 0){
      #pragma unroll
      for (int w = 0; w < NH; ++w) gateV[g][w] = act[w];
    }
    __syncthreads();

    // ---- LSTM cell update (threads 0..9) ----
    if (tid < NH){
      int j = tid;
      float fv = gateV[0][j], iv = gateV[1][j], gv = gateV[2][j], ov = gateV[3][j];
      float cn = fmaf(fv, cxS[j], iv * gv);
      cxS[j] = cn;
      float e2 = __expf(2.f * cn);
      float hn = ov * ((e2 - 1.f) / (e2 + 1.f));
      hxS[j] = hn;
      out[((size_t)t * BATCH + b) * NH + j] = hn;
    }
    __syncthreads();
  }

  // hT, cT
  if (tid < NH){
    const size_t ysN = (size_t)T_STEPS * BATCH * NH;
    out[ysN + (size_t)b * NH + tid]                      = hxS[tid];
    out[ysN + (size_t)BATCH * NH + (size_t)b * NH + tid] = cxS[tid];
  }
}

extern "C" void kernel_launch(void* const* d_in, const int* in_sizes, int n_in,
                              void* d_out, int out_size, void* d_ws, size_t ws_size,
                              hipStream_t stream)
{
  qlstm_kernel<<<BATCH, 256, 0, stream>>>(
      (const float*)d_in[0], (const float*)d_in[1],
      (const float*)d_in[2], (const float*)d_in[3],
      (const float*)d_in[4], (const float*)d_in[5],
      (const float*)d_in[6], (const float*)d_in[7],
      (const float*)d_in[8], (const float*)d_in[9],
      (float*)d_out);
}

// Round 2
// 1599.987 us; speedup vs baseline: 1.6806x; 1.6806x over previous
//
#include <hip/hip_runtime.h>
#include <math.h>

#define T_STEPS 256
#define BATCH   256
#define DDIM    128
#define NH      10

// ---------- wave-wide helpers (wave64) ----------
__device__ __forceinline__ float wave_sum(float v){
  v += __shfl_xor(v, 1, 64);
  v += __shfl_xor(v, 2, 64);
  v += __shfl_xor(v, 4, 64);
  v += __shfl_xor(v, 8, 64);
  v += __shfl_xor(v, 16, 64);
  v += __shfl_xor(v, 32, 64);
  return v;
}

// RX on a reg-bit wire (bit BIT of the 4 low index bits). Pure VALU.
template<int BIT>
__device__ __forceinline__ void rx_reg(float c, float s, float* re, float* im){
  #pragma unroll
  for (int r = 0; r < 16; ++r){
    if (r & (1 << BIT)) continue;
    const int r1 = r | (1 << BIT);
    float a0 = re[r], b0 = im[r], a1 = re[r1], b1 = im[r1];
    re[r]  = fmaf(c, a0,  s * b1);
    im[r]  = fmaf(c, b0, -s * a1);
    re[r1] = fmaf(c, a1,  s * b0);
    im[r1] = fmaf(c, b1, -s * a0);
  }
}

// RX on a lane-bit wire: new_re = c*my_re + s*other_im, new_im = c*my_im - s*other_re.
__device__ __forceinline__ void rx_lane(float c, float s, int mask, float* re, float* im){
  #pragma unroll
  for (int r = 0; r < 16; ++r){
    float oa = __shfl_xor(re[r], mask, 64);
    float ob = __shfl_xor(im[r], mask, 64);
    re[r] = fmaf(c, re[r],  s * ob);
    im[r] = fmaf(c, im[r], -s * oa);
  }
}

// One RX layer over all 10 wires (simple masks). Wire w <-> index bit 9-w.
__device__ __forceinline__ void rx_layer(const float* c, const float* s, float* re, float* im){
  rx_lane(c[0], s[0], 32, re, im);
  rx_lane(c[1], s[1], 16, re, im);
  rx_lane(c[2], s[2],  8, re, im);
  rx_lane(c[3], s[3],  4, re, im);
  rx_lane(c[4], s[4],  2, re, im);
  rx_lane(c[5], s[5],  1, re, im);
  rx_reg<3>(c[6], s[6], re, im);
  rx_reg<2>(c[7], s[7], re, im);
  rx_reg<1>(c[8], s[8], re, im);
  rx_reg<0>(c[9], s[9], re, im);
}

// Circuit algebra (K = composite CNOT-ring index map, s_out[i] = s_in[K i]):
//   dataRX(x); [RX(p); C] x2  ==  build(angles x+p) ; C ; RX(p) ; C
//   == [build evaluated at K j]  ;  RX(p) simple masks  ;  [measure with row_w(K^-1) parity masks]
// K rows (beta_w = wire-w bit of K j):  b_w = wire bit of j, wires 0..5 = lane bits 5..0,
// wires 6..9 = reg bits 3..0:
//   beta0=L5^R0  beta1=L5^L4^R0  beta2=L4^L3  beta3=L3^L2  beta4=L2^L1  beta5=L1^L0
//   beta6=R3^L0  beta7=R2^R3     beta8=R1^R2  beta9=R0^R1
// K^-1 rows (measurement parity masks over j):
//   w0: lane 0x1F, reg 0xF | w1: lane 0x30 | w2: 0x38 | w3: 0x3C | w4: 0x3E | w5: 0x3F
//   w6: lane 0x3F, reg 0x8 | w7: 0x3F,0xC | w8: 0x3F,0xE | w9: 0x3F,0xF
__global__ void __launch_bounds__(256, 1)
qlstm_kernel(const float* __restrict__ inp, const float* __restrict__ rxp,
             const float* __restrict__ Wf, const float* __restrict__ bf,
             const float* __restrict__ Wi, const float* __restrict__ bi,
             const float* __restrict__ Wg, const float* __restrict__ bg,
             const float* __restrict__ Wo, const float* __restrict__ bo,
             float* __restrict__ out)
{
  const int b    = blockIdx.x;
  const int tid  = threadIdx.x;
  const int g    = tid >> 6;     // gate index, wave-uniform
  const int lane = tid & 63;

  __shared__ float gateV[2][4][64];  // double-buffered; padded to 64 lanes
  #pragma unroll
  for (int i = tid; i < 2*4*64; i += 256) ((float*)gateV)[i] = 0.f;

  const float* Wp = (g == 0) ? Wf : (g == 1) ? Wi : (g == 2) ? Wg : Wo;
  const float* bp = (g == 0) ? bf : (g == 1) ? bi : (g == 2) ? bg : bo;

  // Per-lane weight slices; bias folded with rx param (layer-1 RX merge).
  float wA[NH], wB[NH], wC[NH], bT[NH];
  #pragma unroll
  for (int w = 0; w < NH; ++w){
    wA[w] = Wp[w*138 + lane];
    wB[w] = Wp[w*138 + 64 + lane];
    wC[w] = (lane < NH) ? Wp[w*138 + 128 + lane] : 0.f;
    bT[w] = bp[w] + rxp[w];
  }

  // Layer-2 RX params (precise one-time trig).
  float pc[NH], ps[NH];
  #pragma unroll
  for (int w = 0; w < NH; ++w){
    float th = 0.5f * rxp[w];
    pc[w] = cosf(th);
    ps[w] = sinf(th);
  }

  // ---- hoisted lane-dependent constants ----
  const int l5 = (lane>>5)&1, l4 = (lane>>4)&1, l3 = (lane>>3)&1;
  const int l2 = (lane>>2)&1, l1 = (lane>>1)&1, l0 = lane&1;
  const int pb2 = l4^l3, pb3 = l3^l2, pb4 = l2^l1, pb5 = l1^l0;  // build selects, wires 2..5
  const int a0 = l5, a1 = l5^l4, a6 = l0;                         // mixed-wire lane parts
  const int n2345 = pb2 + pb3 + pb4 + pb5;

  // phase constants (-i)^k per reg, k = sum of all beta_w  (step-invariant)
  float cre[16], cim[16];
  #pragma unroll
  for (int r = 0; r < 16; ++r){
    const int R0 = r&1, R1 = (r>>1)&1, R2 = (r>>2)&1, R3 = (r>>3)&1;
    const int b7 = R2^R3, b8 = R1^R2, b9 = R0^R1;
    int k = (n2345 + b7 + b8 + b9 + (a0^R0) + (a1^R0) + (a6^R3)) & 3;
    cre[r] = (k==0) ? 1.f : (k==2) ? -1.f : 0.f;
    cim[r] = (k==1) ? -1.f : (k==3) ? 1.f : 0.f;
  }

  // measurement lane signs
  const float ls0 = (__popc(lane & 0x1F) & 1) ? -1.f : 1.f;
  const float ls1 = (__popc(lane & 0x30) & 1) ? -1.f : 1.f;
  const float ls2 = (__popc(lane & 0x38) & 1) ? -1.f : 1.f;
  const float ls3 = (__popc(lane & 0x3C) & 1) ? -1.f : 1.f;
  const float ls4 = (__popc(lane & 0x3E) & 1) ? -1.f : 1.f;
  const float ls5 = (__popc(lane & 0x3F) & 1) ? -1.f : 1.f;  // shared by w5..w9

  float h = 0.f, c = 0.f;   // per-lane cell state (lane j holds h_j, c_j; j>=10 stays 0)

  // prefetch t=0
  const float* x0 = inp + (size_t)b * DDIM;
  float xa = x0[lane];
  float xb = x0[64 + lane];

  __syncthreads();

  #pragma unroll 1
  for (int t = 0; t < T_STEPS; ++t){
    float xaC = xa, xbC = xb;
    if (t + 1 < T_STEPS){
      const float* nx = inp + ((size_t)(t+1) * BATCH + b) * DDIM;
      xa = nx[lane];
      xb = nx[64 + lane];
    }

    // ---- gate pre-activation angles (half-angles, bias+param folded) ----
    float cs[NH], sn[NH];
    #pragma unroll
    for (int w = 0; w < NH; ++w){
      float p  = fmaf(xaC, wA[w], fmaf(xbC, wB[w], h * wC[w]));
      float th = 0.5f * (bT[w] + wave_sum(p));
      cs[w] = __cosf(th);
      sn[w] = __sinf(th);
    }

    // ---- build u[j] = (product state with angles x+p) evaluated at K j ----
    float f2 = pb2 ? sn[2] : cs[2];
    float f3 = pb3 ? sn[3] : cs[3];
    float f4 = pb4 ? sn[4] : cs[4];
    float f5 = pb5 ? sn[5] : cs[5];
    float m2345 = (f2*f3)*(f4*f5);

    float q0 = (a0 ? sn[0] : cs[0]) * (a1 ? sn[1] : cs[1]);
    float q1 = (a0 ? cs[0] : sn[0]) * (a1 ? cs[1] : sn[1]);
    float v0 = a6 ? sn[6] : cs[6];
    float v1 = a6 ? cs[6] : sn[6];
    float mq0 = m2345 * q0, mq1 = m2345 * q1;
    float Z00 = mq0*v0, Z01 = mq0*v1, Z10 = mq1*v0, Z11 = mq1*v1;

    float A00 = cs[7]*cs[8], A01 = cs[7]*sn[8], A10 = sn[7]*cs[8], A11 = sn[7]*sn[8];

    float re[16], im[16];
    #pragma unroll
    for (int r = 0; r < 16; ++r){
      const int R0 = r&1, R1 = (r>>1)&1, R2 = (r>>2)&1, R3 = (r>>3)&1;
      const int b7 = R2^R3, b8 = R1^R2, b9 = R0^R1;
      float A  = (b7 ? (b8 ? A11 : A10) : (b8 ? A01 : A00));
      float P  = A * (b9 ? sn[9] : cs[9]);
      float Zc = R0 ? (R3 ? Z11 : Z10) : (R3 ? Z01 : Z00);
      float m  = P * Zc;
      re[r] = m * cre[r];
      im[r] = m * cim[r];
    }

    // ---- layer-2 RX (simple masks; CNOT rings folded out) ----
    rx_layer(pc, ps, re, im);

    // ---- PauliZ expectations with K^-1 parity masks ----
    float tot = 0.f, q8 = 0.f, qC = 0.f, qE = 0.f, qF = 0.f;
    #pragma unroll
    for (int r = 0; r < 16; ++r){
      float p = fmaf(re[r], re[r], im[r]*im[r]);
      tot += p;
      q8 += ((__popc(r & 0x8) & 1) ? -p : p);
      qC += ((__popc(r & 0xC) & 1) ? -p : p);
      qE += ((__popc(r & 0xE) & 1) ? -p : p);
      qF += ((__popc(r & 0xF) & 1) ? -p : p);
    }
    float e[NH];
    e[0] = wave_sum(ls0 * qF);
    e[1] = wave_sum(ls1 * tot);
    e[2] = wave_sum(ls2 * tot);
    e[3] = wave_sum(ls3 * tot);
    e[4] = wave_sum(ls4 * tot);
    e[5] = wave_sum(ls5 * tot);
    e[6] = wave_sum(ls5 * q8);
    e[7] = wave_sum(ls5 * qC);
    e[8] = wave_sum(ls5 * qE);
    e[9] = wave_sum(ls5 * qF);

    // ---- activation (wave-uniform branch) ----
    float act[NH];
    if (g == 2){
      #pragma unroll
      for (int w = 0; w < NH; ++w){
        float e2 = __expf(2.f * e[w]);
        act[w] = (e2 - 1.f) / (e2 + 1.f);
      }
    } else {
      #pragma unroll
      for (int w = 0; w < NH; ++w){
        act[w] = 1.f / (1.f + __expf(-e[w]));
      }
    }
    if (lane == 0){
      #pragma unroll
      for (int w = 0; w < NH; ++w) gateV[t & 1][g][w] = act[w];
    }
    __syncthreads();

    // ---- per-lane redundant cell update (h_j, c_j in lane j's registers) ----
    float fv = gateV[t & 1][0][lane];
    float iv = gateV[t & 1][1][lane];
    float gv = gateV[t & 1][2][lane];
    float ov = gateV[t & 1][3][lane];
    c = fmaf(fv, c, iv * gv);
    float e2c = __expf(2.f * c);
    h = ov * ((e2c - 1.f) / (e2c + 1.f));

    if (g == 0 && lane < NH)
      out[((size_t)t * BATCH + b) * NH + lane] = h;
  }

  // hT, cT
  if (g == 0 && lane < NH){
    const size_t ysN = (size_t)T_STEPS * BATCH * NH;
    out[ysN + (size_t)b * NH + lane]                      = h;
    out[ysN + (size_t)BATCH * NH + (size_t)b * NH + lane] = c;
  }
}

extern "C" void kernel_launch(void* const* d_in, const int* in_sizes, int n_in,
                              void* d_out, int out_size, void* d_ws, size_t ws_size,
                              hipStream_t stream)
{
  qlstm_kernel<<<BATCH, 256, 0, stream>>>(
      (const float*)d_in[0], (const float*)d_in[1],
      (const float*)d_in[2], (const float*)d_in[3],
      (const float*)d_in[4], (const float*)d_in[5],
      (const float*)d_in[6], (const float*)d_in[7],
      (const float*)d_in[8], (const float*)d_in[9],
      (float*)d_out);
}

// Round 4
// 1382.074 us; speedup vs baseline: 1.9456x; 1.1577x over previous
//
#include <hip/hip_runtime.h>
#include <math.h>

#define T_STEPS 256
#define BATCH   256
#define DDIM    128
#define NH      10

// ---------- DPP reduction (canonical GCN wave64 ladder, VALU pipe) ----------
// update_dpp(old, src, dpp_ctrl, row_mask, bank_mask, bound_ctrl)
// old=0 + bound_ctrl=true: any masked-off or invalid-source lane contributes 0.
template<int CTRL, int RMASK, int BMASK>
__device__ __forceinline__ float dppz(float x){
  return __int_as_float(__builtin_amdgcn_update_dpp(
      0, __float_as_int(x), CTRL, RMASK, BMASK, true));
}

// After this ladder lane 63 holds the full 64-lane sum (textbook sequence:
// row_shr:1,2,4,8 then row_bcast:15,31 with the canonical masks).
__device__ __forceinline__ float red63(float v){
  v += dppz<0x111, 0xF, 0xF>(v);   // row_shr:1
  v += dppz<0x112, 0xF, 0xF>(v);   // row_shr:2
  v += dppz<0x114, 0xF, 0xE>(v);   // row_shr:4  bank_mask:0xe
  v += dppz<0x118, 0xF, 0xC>(v);   // row_shr:8  bank_mask:0xc
  v += dppz<0x142, 0xA, 0xF>(v);   // row_bcast:15 row_mask:0xa
  v += dppz<0x143, 0xC, 0xF>(v);   // row_bcast:31 row_mask:0xc
  return v;
}
// full wave sum broadcast to all lanes (via SGPR readlane of lane 63)
__device__ __forceinline__ float wave_sum_b(float v){
  return __int_as_float(__builtin_amdgcn_readlane(__float_as_int(red63(v)), 63));
}

// RX on a reg-bit wire (bit BIT of the 4 low index bits). Pure VALU.
template<int BIT>
__device__ __forceinline__ void rx_reg(float c, float s, float* re, float* im){
  #pragma unroll
  for (int r = 0; r < 16; ++r){
    if (r & (1 << BIT)) continue;
    const int r1 = r | (1 << BIT);
    float a0 = re[r], b0 = im[r], a1 = re[r1], b1 = im[r1];
    re[r]  = fmaf(c, a0,  s * b1);
    im[r]  = fmaf(c, b0, -s * a1);
    re[r1] = fmaf(c, a1,  s * b0);
    im[r1] = fmaf(c, b1, -s * a0);
  }
}

// RX on a lane-bit wire via known-good __shfl_xor (ds pipe):
// new_re = c*re + s*im_partner, new_im = c*im - s*re_partner.
__device__ __forceinline__ void rx_lane(float c, float s, int mask, float* re, float* im){
  #pragma unroll
  for (int r = 0; r < 16; ++r){
    float oa = __shfl_xor(re[r], mask, 64);
    float ob = __shfl_xor(im[r], mask, 64);
    re[r] = fmaf(c, re[r],  s * ob);
    im[r] = fmaf(c, im[r], -s * oa);
  }
}

// One RX layer over all 10 wires. Wire w <-> index bit 9-w.
__device__ __forceinline__ void rx_layer(const float* c, const float* s, float* re, float* im){
  rx_lane(c[0], s[0], 32, re, im);
  rx_lane(c[1], s[1], 16, re, im);
  rx_lane(c[2], s[2],  8, re, im);
  rx_lane(c[3], s[3],  4, re, im);
  rx_lane(c[4], s[4],  2, re, im);
  rx_lane(c[5], s[5],  1, re, im);
  rx_reg<3>(c[6], s[6], re, im);
  rx_reg<2>(c[7], s[7], re, im);
  rx_reg<1>(c[8], s[8], re, im);
  rx_reg<0>(c[9], s[9], re, im);
}

// Circuit algebra (K = composite CNOT-ring index map, s_out[i] = s_in[K i]):
//   dataRX(x); [RX(p); C] x2  ==  [build product state at K j] ; RX(p) ; [measure
//   with row_w(K^-1) parity masks].  See R1/R2 notes for the K / K^-1 rows.
__global__ void __launch_bounds__(256, 1)
qlstm_kernel(const float* __restrict__ inp, const float* __restrict__ rxp,
             const float* __restrict__ Wf, const float* __restrict__ bf,
             const float* __restrict__ Wi, const float* __restrict__ bi,
             const float* __restrict__ Wg, const float* __restrict__ bg,
             const float* __restrict__ Wo, const float* __restrict__ bo,
             float* __restrict__ out)
{
  const int b    = blockIdx.x;
  const int tid  = threadIdx.x;
  const int g    = tid >> 6;     // gate index, wave-uniform
  const int lane = tid & 63;

  __shared__ float gateV[2][4][64];  // double-buffered; padded to 64 lanes
  #pragma unroll
  for (int i = tid; i < 2*4*64; i += 256) ((float*)gateV)[i] = 0.f;

  const float* Wp = (g == 0) ? Wf : (g == 1) ? Wi : (g == 2) ? Wg : Wo;
  const float* bp = (g == 0) ? bf : (g == 1) ? bi : (g == 2) ? bg : bo;

  // Per-lane weight slices; bias folded with rx param (layer-1 RX merge).
  float wA[NH], wB[NH], wC[NH], bT[NH];
  #pragma unroll
  for (int w = 0; w < NH; ++w){
    wA[w] = Wp[w*138 + lane];
    wB[w] = Wp[w*138 + 64 + lane];
    wC[w] = (lane < NH) ? Wp[w*138 + 128 + lane] : 0.f;
    bT[w] = bp[w] + rxp[w];
  }

  // Layer-2 RX params (precise one-time trig).
  float pc[NH], ps[NH];
  #pragma unroll
  for (int w = 0; w < NH; ++w){
    float th = 0.5f * rxp[w];
    pc[w] = cosf(th);
    ps[w] = sinf(th);
  }

  // ---- hoisted lane-dependent constants ----
  const int l5 = (lane>>5)&1, l4 = (lane>>4)&1, l3 = (lane>>3)&1;
  const int l2 = (lane>>2)&1, l1 = (lane>>1)&1, l0 = lane&1;
  const int pb2 = l4^l3, pb3 = l3^l2, pb4 = l2^l1, pb5 = l1^l0;  // build selects, wires 2..5
  const int a0 = l5, a1 = l5^l4, a6 = l0;                         // mixed-wire lane parts
  const int n2345 = pb2 + pb3 + pb4 + pb5;

  // phase constants (-i)^k per reg (step-invariant)
  float cre[16], cim[16];
  #pragma unroll
  for (int r = 0; r < 16; ++r){
    const int R0 = r&1, R1 = (r>>1)&1, R2 = (r>>2)&1, R3 = (r>>3)&1;
    const int b7 = R2^R3, b8 = R1^R2, b9 = R0^R1;
    int k = (n2345 + b7 + b8 + b9 + (a0^R0) + (a1^R0) + (a6^R3)) & 3;
    cre[r] = (k==0) ? 1.f : (k==2) ? -1.f : 0.f;
    cim[r] = (k==1) ? -1.f : (k==3) ? 1.f : 0.f;
  }

  // measurement lane signs
  const float ls0 = (__popc(lane & 0x1F) & 1) ? -1.f : 1.f;
  const float ls1 = (__popc(lane & 0x30) & 1) ? -1.f : 1.f;
  const float ls2 = (__popc(lane & 0x38) & 1) ? -1.f : 1.f;
  const float ls3 = (__popc(lane & 0x3C) & 1) ? -1.f : 1.f;
  const float ls4 = (__popc(lane & 0x3E) & 1) ? -1.f : 1.f;
  const float ls5 = (__popc(lane & 0x3F) & 1) ? -1.f : 1.f;  // shared by w5..w9

  float h = 0.f, c = 0.f;   // per-lane cell state (lane j holds h_j, c_j; j>=10 stays 0)

  // prefetch t=0
  const float* x0 = inp + (size_t)b * DDIM;
  float xa = x0[lane];
  float xb = x0[64 + lane];

  __syncthreads();

  #pragma unroll 1
  for (int t = 0; t < T_STEPS; ++t){
    float xaC = xa, xbC = xb;
    if (t + 1 < T_STEPS){
      const float* nx = inp + ((size_t)(t+1) * BATCH + b) * DDIM;
      xa = nx[lane];
      xb = nx[64 + lane];
    }

    // ---- gate pre-activation angles (half-angles, bias+param folded) ----
    float cs[NH], sn[NH];
    #pragma unroll
    for (int w = 0; w < NH; ++w){
      float p  = fmaf(xaC, wA[w], fmaf(xbC, wB[w], h * wC[w]));
      float th = 0.5f * (bT[w] + wave_sum_b(p));
      cs[w] = __cosf(th);
      sn[w] = __sinf(th);
    }

    // ---- build u[j] = (product state with angles x+p) evaluated at K j ----
    float f2 = pb2 ? sn[2] : cs[2];
    float f3 = pb3 ? sn[3] : cs[3];
    float f4 = pb4 ? sn[4] : cs[4];
    float f5 = pb5 ? sn[5] : cs[5];
    float m2345 = (f2*f3)*(f4*f5);

    float q0 = (a0 ? sn[0] : cs[0]) * (a1 ? sn[1] : cs[1]);
    float q1 = (a0 ? cs[0] : sn[0]) * (a1 ? cs[1] : sn[1]);
    float v0 = a6 ? sn[6] : cs[6];
    float v1 = a6 ? cs[6] : sn[6];
    float mq0 = m2345 * q0, mq1 = m2345 * q1;
    float Z00 = mq0*v0, Z01 = mq0*v1, Z10 = mq1*v0, Z11 = mq1*v1;

    float A00 = cs[7]*cs[8], A01 = cs[7]*sn[8], A10 = sn[7]*cs[8], A11 = sn[7]*sn[8];

    float re[16], im[16];
    #pragma unroll
    for (int r = 0; r < 16; ++r){
      const int R0 = r&1, R1 = (r>>1)&1, R2 = (r>>2)&1, R3 = (r>>3)&1;
      const int b7 = R2^R3, b8 = R1^R2, b9 = R0^R1;
      float A  = (b7 ? (b8 ? A11 : A10) : (b8 ? A01 : A00));
      float P  = A * (b9 ? sn[9] : cs[9]);
      float Zc = R0 ? (R3 ? Z11 : Z10) : (R3 ? Z01 : Z00);
      float m  = P * Zc;
      re[r] = m * cre[r];
      im[r] = m * cim[r];
    }

    // ---- layer-2 RX (simple masks; CNOT rings folded out) ----
    rx_layer(pc, ps, re, im);

    // ---- PauliZ expectations with K^-1 parity masks; totals land in lane 63 ----
    float tot = 0.f, q8 = 0.f, qC = 0.f, qE = 0.f, qF = 0.f;
    #pragma unroll
    for (int r = 0; r < 16; ++r){
      float p = fmaf(re[r], re[r], im[r]*im[r]);
      tot += p;
      q8 += ((__popc(r & 0x8) & 1) ? -p : p);
      qC += ((__popc(r & 0xC) & 1) ? -p : p);
      qE += ((__popc(r & 0xE) & 1) ? -p : p);
      qF += ((__popc(r & 0xF) & 1) ? -p : p);
    }
    float e[NH];
    e[0] = red63(ls0 * qF);
    e[1] = red63(ls1 * tot);
    e[2] = red63(ls2 * tot);
    e[3] = red63(ls3 * tot);
    e[4] = red63(ls4 * tot);
    e[5] = red63(ls5 * tot);
    e[6] = red63(ls5 * q8);
    e[7] = red63(ls5 * qC);
    e[8] = red63(ls5 * qE);
    e[9] = red63(ls5 * qF);

    // ---- activation; only lane 63's values are meaningful/stored ----
    float act[NH];
    if (g == 2){
      #pragma unroll
      for (int w = 0; w < NH; ++w){
        float e2 = __expf(2.f * e[w]);
        act[w] = (e2 - 1.f) / (e2 + 1.f);
      }
    } else {
      #pragma unroll
      for (int w = 0; w < NH; ++w){
        act[w] = 1.f / (1.f + __expf(-e[w]));
      }
    }
    if (lane == 63){
      #pragma unroll
      for (int w = 0; w < NH; ++w) gateV[t & 1][g][w] = act[w];
    }
    __syncthreads();

    // ---- per-lane redundant cell update (h_j, c_j in lane j's registers) ----
    float fv = gateV[t & 1][0][lane];
    float iv = gateV[t & 1][1][lane];
    float gv = gateV[t & 1][2][lane];
    float ov = gateV[t & 1][3][lane];
    c = fmaf(fv, c, iv * gv);
    float e2c = __expf(2.f * c);
    h = ov * ((e2c - 1.f) / (e2c + 1.f));

    if (g == 0 && lane < NH)
      out[((size_t)t * BATCH + b) * NH + lane] = h;
  }

  // hT, cT
  if (g == 0 && lane < NH){
    const size_t ysN = (size_t)T_STEPS * BATCH * NH;
    out[ysN + (size_t)b * NH + lane]                      = h;
    out[ysN + (size_t)BATCH * NH + (size_t)b * NH + lane] = c;
  }
}

extern "C" void kernel_launch(void* const* d_in, const int* in_sizes, int n_in,
                              void* d_out, int out_size, void* d_ws, size_t ws_size,
                              hipStream_t stream)
{
  qlstm_kernel<<<BATCH, 256, 0, stream>>>(
      (const float*)d_in[0], (const float*)d_in[1],
      (const float*)d_in[2], (const float*)d_in[3],
      (const float*)d_in[4], (const float*)d_in[5],
      (const float*)d_in[6], (const float*)d_in[7],
      (const float*)d_in[8], (const float*)d_in[9],
      (float*)d_out);
}

// Round 5
// 1245.425 us; speedup vs baseline: 2.1591x; 1.1097x over previous
//
#include <hip/hip_runtime.h>
#include <math.h>

#define T_STEPS 256
#define BATCH   256
#define DDIM    128
#define NH      10

// ---------- DPP helpers (VALU pipe) ----------
// update_dpp(old, src, dpp_ctrl, row_mask, bank_mask, bound_ctrl)
template<int CTRL, int RMASK, int BMASK>
__device__ __forceinline__ float dppz(float x){
  return __int_as_float(__builtin_amdgcn_update_dpp(
      0, __float_as_int(x), CTRL, RMASK, BMASK, true));
}

// quad_perm full-lane permute (all sources valid; standard rocPRIM idiom)
template<int CTRL>
__device__ __forceinline__ float qperm(float x){
  int xi = __float_as_int(x);
  return __int_as_float(__builtin_amdgcn_update_dpp(xi, xi, CTRL, 0xF, 0xF, false));
}

// Canonical wave64 ladder: after this, lane 63 holds the full sum. (Verified R4.)
__device__ __forceinline__ float red63(float v){
  v += dppz<0x111, 0xF, 0xF>(v);   // row_shr:1
  v += dppz<0x112, 0xF, 0xF>(v);   // row_shr:2
  v += dppz<0x114, 0xF, 0xE>(v);   // row_shr:4  bank_mask:0xe
  v += dppz<0x118, 0xF, 0xC>(v);   // row_shr:8  bank_mask:0xc
  v += dppz<0x142, 0xA, 0xF>(v);   // row_bcast:15 row_mask:0xa
  v += dppz<0x143, 0xC, 0xF>(v);   // row_bcast:31 row_mask:0xc
  return v;
}
// full wave sum broadcast to all lanes (via SGPR readlane of lane 63)
__device__ __forceinline__ float wave_sum_b(float v){
  return __int_as_float(__builtin_amdgcn_readlane(__float_as_int(red63(v)), 63));
}

// RX on a reg-bit wire (bit BIT of the 4 low index bits). Pure VALU.
template<int BIT>
__device__ __forceinline__ void rx_reg(float c, float s, float* re, float* im){
  #pragma unroll
  for (int r = 0; r < 16; ++r){
    if (r & (1 << BIT)) continue;
    const int r1 = r | (1 << BIT);
    float a0 = re[r], b0 = im[r], a1 = re[r1], b1 = im[r1];
    re[r]  = fmaf(c, a0,  s * b1);
    im[r]  = fmaf(c, b0, -s * a1);
    re[r1] = fmaf(c, a1,  s * b0);
    im[r1] = fmaf(c, b1, -s * a0);
  }
}

// RX on a lane-bit wire via __shfl_xor (ds pipe; known-good):
__device__ __forceinline__ void rx_lane(float c, float s, int mask, float* re, float* im){
  #pragma unroll
  for (int r = 0; r < 16; ++r){
    float oa = __shfl_xor(re[r], mask, 64);
    float ob = __shfl_xor(im[r], mask, 64);
    re[r] = fmaf(c, re[r],  s * ob);
    im[r] = fmaf(c, im[r], -s * oa);
  }
}

// RX on a lane-bit wire via quad_perm DPP (masks 1, 2 only; VALU pipe)
template<int CTRL>
__device__ __forceinline__ void rx_lane_qp(float c, float s, float* re, float* im){
  #pragma unroll
  for (int r = 0; r < 16; ++r){
    float oa = qperm<CTRL>(re[r]);
    float ob = qperm<CTRL>(im[r]);
    re[r] = fmaf(c, re[r],  s * ob);
    im[r] = fmaf(c, im[r], -s * oa);
  }
}

// One RX layer over all 10 wires. Wire w <-> index bit 9-w.
// Single-qubit RX gates on distinct wires commute -> stage order is free.
// ds stages (masks 32,16,8,4) first, then DPP quad_perm stages (2,1), then reg wires.
__device__ __forceinline__ void rx_layer(const float* c, const float* s, float* re, float* im){
  rx_lane(c[0], s[0], 32, re, im);
  rx_lane(c[1], s[1], 16, re, im);
  rx_lane(c[2], s[2],  8, re, im);
  rx_lane(c[3], s[3],  4, re, im);
  rx_lane_qp<0x4E>(c[4], s[4], re, im);  // xor-2: quad_perm(2,3,0,1)
  rx_lane_qp<0xB1>(c[5], s[5], re, im);  // xor-1: quad_perm(1,0,3,2)
  rx_reg<3>(c[6], s[6], re, im);
  rx_reg<2>(c[7], s[7], re, im);
  rx_reg<1>(c[8], s[8], re, im);
  rx_reg<0>(c[9], s[9], re, im);
}

// Circuit algebra (K = composite CNOT-ring index map, s_out[i] = s_in[K i]):
//   dataRX(x); [RX(p); C] x2  ==  [build product state at K j] ; RX(p) ; [measure
//   with row_w(K^-1) parity masks].  See R1/R2 notes for the K / K^-1 rows.
__global__ void __launch_bounds__(256)
__attribute__((amdgpu_waves_per_eu(1, 1)))   // grid-limited to 1 wave/EU anyway:
                                             // free the register allocator (was VGPR=64
                                             // with heavy AGPR shuttling)
qlstm_kernel(const float* __restrict__ inp, const float* __restrict__ rxp,
             const float* __restrict__ Wf, const float* __restrict__ bf,
             const float* __restrict__ Wi, const float* __restrict__ bi,
             const float* __restrict__ Wg, const float* __restrict__ bg,
             const float* __restrict__ Wo, const float* __restrict__ bo,
             float* __restrict__ out)
{
  const int b    = blockIdx.x;
  const int tid  = threadIdx.x;
  const int g    = tid >> 6;     // gate index, wave-uniform
  const int lane = tid & 63;

  __shared__ float gateV[2][4][64];  // double-buffered; padded to 64 lanes
  #pragma unroll
  for (int i = tid; i < 2*4*64; i += 256) ((float*)gateV)[i] = 0.f;

  const float* Wp = (g == 0) ? Wf : (g == 1) ? Wi : (g == 2) ? Wg : Wo;
  const float* bp = (g == 0) ? bf : (g == 1) ? bi : (g == 2) ? bg : bo;

  // Per-lane weight slices; bias folded with rx param (layer-1 RX merge).
  float wA[NH], wB[NH], wC[NH], bT[NH];
  #pragma unroll
  for (int w = 0; w < NH; ++w){
    wA[w] = Wp[w*138 + lane];
    wB[w] = Wp[w*138 + 64 + lane];
    wC[w] = (lane < NH) ? Wp[w*138 + 128 + lane] : 0.f;
    bT[w] = bp[w] + rxp[w];
  }

  // Layer-2 RX params (precise one-time trig).
  float pc[NH], ps[NH];
  #pragma unroll
  for (int w = 0; w < NH; ++w){
    float th = 0.5f * rxp[w];
    pc[w] = cosf(th);
    ps[w] = sinf(th);
  }

  // ---- hoisted lane-dependent constants ----
  const int l5 = (lane>>5)&1, l4 = (lane>>4)&1, l3 = (lane>>3)&1;
  const int l2 = (lane>>2)&1, l1 = (lane>>1)&1, l0 = lane&1;
  const int pb2 = l4^l3, pb3 = l3^l2, pb4 = l2^l1, pb5 = l1^l0;  // build selects, wires 2..5
  const int a0 = l5, a1 = l5^l4, a6 = l0;                         // mixed-wire lane parts
  const int n2345 = pb2 + pb3 + pb4 + pb5;

  // phase constants (-i)^k per reg (step-invariant)
  float cre[16], cim[16];
  #pragma unroll
  for (int r = 0; r < 16; ++r){
    const int R0 = r&1, R1 = (r>>1)&1, R2 = (r>>2)&1, R3 = (r>>3)&1;
    const int b7 = R2^R3, b8 = R1^R2, b9 = R0^R1;
    int k = (n2345 + b7 + b8 + b9 + (a0^R0) + (a1^R0) + (a6^R3)) & 3;
    cre[r] = (k==0) ? 1.f : (k==2) ? -1.f : 0.f;
    cim[r] = (k==1) ? -1.f : (k==3) ? 1.f : 0.f;
  }

  // measurement lane signs
  const float ls0 = (__popc(lane & 0x1F) & 1) ? -1.f : 1.f;
  const float ls1 = (__popc(lane & 0x30) & 1) ? -1.f : 1.f;
  const float ls2 = (__popc(lane & 0x38) & 1) ? -1.f : 1.f;
  const float ls3 = (__popc(lane & 0x3C) & 1) ? -1.f : 1.f;
  const float ls4 = (__popc(lane & 0x3E) & 1) ? -1.f : 1.f;
  const float ls5 = (__popc(lane & 0x3F) & 1) ? -1.f : 1.f;  // shared by w5..w9

  float h = 0.f, c = 0.f;   // per-lane cell state (lane j holds h_j, c_j; j>=10 stays 0)

  // prefetch t=0
  const float* x0 = inp + (size_t)b * DDIM;
  float xa = x0[lane];
  float xb = x0[64 + lane];

  __syncthreads();

  #pragma unroll 1
  for (int t = 0; t < T_STEPS; ++t){
    float xaC = xa, xbC = xb;
    if (t + 1 < T_STEPS){
      const float* nx = inp + ((size_t)(t+1) * BATCH + b) * DDIM;
      xa = nx[lane];
      xb = nx[64 + lane];
    }

    // ---- gate pre-activation angles (half-angles, bias+param folded) ----
    float cs[NH], sn[NH];
    #pragma unroll
    for (int w = 0; w < NH; ++w){
      float p  = fmaf(xaC, wA[w], fmaf(xbC, wB[w], h * wC[w]));
      float th = 0.5f * (bT[w] + wave_sum_b(p));
      cs[w] = __cosf(th);
      sn[w] = __sinf(th);
    }

    // ---- build u[j] = (product state with angles x+p) evaluated at K j ----
    float f2 = pb2 ? sn[2] : cs[2];
    float f3 = pb3 ? sn[3] : cs[3];
    float f4 = pb4 ? sn[4] : cs[4];
    float f5 = pb5 ? sn[5] : cs[5];
    float m2345 = (f2*f3)*(f4*f5);

    float q0 = (a0 ? sn[0] : cs[0]) * (a1 ? sn[1] : cs[1]);
    float q1 = (a0 ? cs[0] : sn[0]) * (a1 ? cs[1] : sn[1]);
    float v0 = a6 ? sn[6] : cs[6];
    float v1 = a6 ? cs[6] : sn[6];
    float mq0 = m2345 * q0, mq1 = m2345 * q1;
    float Z00 = mq0*v0, Z01 = mq0*v1, Z10 = mq1*v0, Z11 = mq1*v1;

    float A00 = cs[7]*cs[8], A01 = cs[7]*sn[8], A10 = sn[7]*cs[8], A11 = sn[7]*sn[8];

    float re[16], im[16];
    #pragma unroll
    for (int r = 0; r < 16; ++r){
      const int R0 = r&1, R1 = (r>>1)&1, R2 = (r>>2)&1, R3 = (r>>3)&1;
      const int b7 = R2^R3, b8 = R1^R2, b9 = R0^R1;
      float A  = (b7 ? (b8 ? A11 : A10) : (b8 ? A01 : A00));
      float P  = A * (b9 ? sn[9] : cs[9]);
      float Zc = R0 ? (R3 ? Z11 : Z10) : (R3 ? Z01 : Z00);
      float m  = P * Zc;
      re[r] = m * cre[r];
      im[r] = m * cim[r];
    }

    // ---- layer-2 RX (simple masks; CNOT rings folded out) ----
    rx_layer(pc, ps, re, im);

    // ---- PauliZ expectations with K^-1 parity masks; totals land in lane 63 ----
    float tot = 0.f, q8 = 0.f, qC = 0.f, qE = 0.f, qF = 0.f;
    #pragma unroll
    for (int r = 0; r < 16; ++r){
      float p = fmaf(re[r], re[r], im[r]*im[r]);
      tot += p;
      q8 += ((__popc(r & 0x8) & 1) ? -p : p);
      qC += ((__popc(r & 0xC) & 1) ? -p : p);
      qE += ((__popc(r & 0xE) & 1) ? -p : p);
      qF += ((__popc(r & 0xF) & 1) ? -p : p);
    }
    float e[NH];
    e[0] = red63(ls0 * qF);
    e[1] = red63(ls1 * tot);
    e[2] = red63(ls2 * tot);
    e[3] = red63(ls3 * tot);
    e[4] = red63(ls4 * tot);
    e[5] = red63(ls5 * tot);
    e[6] = red63(ls5 * q8);
    e[7] = red63(ls5 * qC);
    e[8] = red63(ls5 * qE);
    e[9] = red63(ls5 * qF);

    // ---- activation; only lane 63's values are meaningful/stored ----
    float act[NH];
    if (g == 2){
      #pragma unroll
      for (int w = 0; w < NH; ++w){
        float e2 = __expf(2.f * e[w]);
        act[w] = (e2 - 1.f) / (e2 + 1.f);
      }
    } else {
      #pragma unroll
      for (int w = 0; w < NH; ++w){
        act[w] = 1.f / (1.f + __expf(-e[w]));
      }
    }
    if (lane == 63){
      #pragma unroll
      for (int w = 0; w < NH; ++w) gateV[t & 1][g][w] = act[w];
    }
    __syncthreads();

    // ---- per-lane redundant cell update (h_j, c_j in lane j's registers) ----
    float fv = gateV[t & 1][0][lane];
    float iv = gateV[t & 1][1][lane];
    float gv = gateV[t & 1][2][lane];
    float ov = gateV[t & 1][3][lane];
    c = fmaf(fv, c, iv * gv);
    float e2c = __expf(2.f * c);
    h = ov * ((e2c - 1.f) / (e2c + 1.f));

    if (g == 0 && lane < NH)
      out[((size_t)t * BATCH + b) * NH + lane] = h;
  }

  // hT, cT
  if (g == 0 && lane < NH){
    const size_t ysN = (size_t)T_STEPS * BATCH * NH;
    out[ysN + (size_t)b * NH + lane]                      = h;
    out[ysN + (size_t)BATCH * NH + (size_t)b * NH + lane] = c;
  }
}

extern "C" void kernel_launch(void* const* d_in, const int* in_sizes, int n_in,
                              void* d_out, int out_size, void* d_ws, size_t ws_size,
                              hipStream_t stream)
{
  qlstm_kernel<<<BATCH, 256, 0, stream>>>(
      (const float*)d_in[0], (const float*)d_in[1],
      (const float*)d_in[2], (const float*)d_in[3],
      (const float*)d_in[4], (const float*)d_in[5],
      (const float*)d_in[6], (const float*)d_in[7],
      (const float*)d_in[8], (const float*)d_in[9],
      (float*)d_out);
}